// Round 7
// baseline (208.697 us; speedup 1.0000x reference)
//
#include <hip/hip_runtime.h>
#include <hip/hip_bf16.h>

#define H 128
#define O 64
#define RELS 4

typedef short short8 __attribute__((ext_vector_type(8)));
typedef float f32x4 __attribute__((ext_vector_type(4)));

static __device__ __forceinline__ unsigned short f2b(float x) {
    __hip_bfloat16 h = __float2bfloat16(x);           // RNE
    return *reinterpret_cast<unsigned short*>(&h);
}
static __device__ __forceinline__ float blo(unsigned u) { return __uint_as_float(u << 16); }
static __device__ __forceinline__ float bhi(unsigned u) { return __uint_as_float(u & 0xffff0000u); }

// NOTE: parameter names must not collide with vector member names (.x/.y/.z/.w)
#define ACC8(acc, uv, wt)                                           \
    acc[0] += (wt) * blo(uv.x); acc[1] += (wt) * bhi(uv.x);         \
    acc[2] += (wt) * blo(uv.y); acc[3] += (wt) * bhi(uv.y);         \
    acc[4] += (wt) * blo(uv.z); acc[5] += (wt) * bhi(uv.z);         \
    acc[6] += (wt) * blo(uv.w); acc[7] += (wt) * bhi(uv.w);

// 8 slots starting at compile-time base B_
#define ACC8B(acc, B_, uv, wt)                                              \
    acc[(B_)+0] += (wt) * blo(uv.x); acc[(B_)+1] += (wt) * bhi(uv.x);       \
    acc[(B_)+2] += (wt) * blo(uv.y); acc[(B_)+3] += (wt) * bhi(uv.y);       \
    acc[(B_)+4] += (wt) * blo(uv.z); acc[(B_)+5] += (wt) * bhi(uv.z);       \
    acc[(B_)+6] += (wt) * blo(uv.w); acc[(B_)+7] += (wt) * bhi(uv.w);

// ---------- fused prep: embed->bf16 (4x ILP), W->WT2 [n][r*128+k] bf16, dst histogram ----------
__global__ void k_prep(const float* __restrict__ embed, unsigned short* __restrict__ eb,
                       const float* __restrict__ W, unsigned short* __restrict__ WT2,
                       const int* __restrict__ dst, int* __restrict__ cnt,
                       int n4, int wtot, int E, int RE, int N, int b_cvt, int b_w) {
    int b = blockIdx.x;
    if (b < b_cvt) {
        int base = b * 1024;
#pragma unroll
        for (int k = 0; k < 4; ++k) {
            int i = base + k * 256 + threadIdx.x;
            if (i < n4) {
                float4 v = ((const float4*)embed)[i];
                ushort4 o;
                o.x = f2b(v.x); o.y = f2b(v.y); o.z = f2b(v.z); o.w = f2b(v.w);
                ((ushort4*)eb)[i] = o;
            }
        }
    } else if (b < b_cvt + b_w) {
        int i = (b - b_cvt) * 256 + threadIdx.x;
        if (i < wtot) {
            int n = i >> 9;             // 512 k_cat per output col
            int kcat = i & 511;
            int r = kcat >> 7;
            int k = kcat & (H - 1);
            WT2[i] = f2b(W[((size_t)r * H + k) * O + n]);
        }
    } else {
        int i = (b - b_cvt - b_w) * 256 + threadIdx.x;
        if (i < RE) { int r = i / E; atomicAdd(&cnt[r * N + dst[i]], 1); }
    }
}

// ---------- scan1 with fused per-node total (totdeg = sum_r cnt[r*N+i]) ----------
__global__ void k_scan1(const int* __restrict__ cnt, int* __restrict__ offs,
                        int* __restrict__ bsum, int n, int N_) {
    __shared__ int sh[256];
    int t = threadIdx.x;
    int base = blockIdx.x * 1024 + t * 4;
    int4 v = make_int4(0, 0, 0, 0);
    if (base + 3 < n && (N_ & 3) == 0) {
#pragma unroll
        for (int r = 0; r < RELS; ++r) {
            int4 c = *(const int4*)(cnt + (size_t)r * N_ + base);
            v.x += c.x; v.y += c.y; v.z += c.z; v.w += c.w;
        }
    } else {
        for (int j = 0; j < 4; ++j) {
            int i = base + j;
            if (i < n) {
                int s = 0;
                for (int r = 0; r < RELS; ++r) s += cnt[(size_t)r * N_ + i];
                (&v.x)[j] = s;
            }
        }
    }
    int s = v.x + v.y + v.z + v.w;
    sh[t] = s; __syncthreads();
    for (int off = 1; off < 256; off <<= 1) {
        int x = (t >= off) ? sh[t - off] : 0;
        __syncthreads();
        sh[t] += x;
        __syncthreads();
    }
    int incl = sh[t];
    int ex = incl - s;
    if (base < n)     offs[base]     = ex;
    if (base + 1 < n) offs[base + 1] = ex + v.x;
    if (base + 2 < n) offs[base + 2] = ex + v.x + v.y;
    if (base + 3 < n) offs[base + 3] = ex + v.x + v.y + v.z;
    if (t == 255) bsum[blockIdx.x] = incl;
}

__global__ void k_scan2(int* __restrict__ bsum, int nb) {
    __shared__ int sh[512];
    int t = threadIdx.x;
    int s = (t < nb) ? bsum[t] : 0;
    sh[t] = s; __syncthreads();
    for (int off = 1; off < 512; off <<= 1) {
        int x = (t >= off) ? sh[t - off] : 0;
        __syncthreads();
        sh[t] += x;
        __syncthreads();
    }
    if (t < nb) bsum[t] = sh[t] - s;
}

// finalize offs + build per-(rel,node) cursors
__global__ void k_scan3c(int* __restrict__ offs, const int* __restrict__ bsum,
                         const int* __restrict__ cnt, int* __restrict__ cursor,
                         int n, int total, int N_) {
    int i = blockIdx.x * blockDim.x + threadIdx.x;
    if (i < n) {
        int off = offs[i] + bsum[i >> 10];
        offs[i] = off;
        int c0 = cnt[i], c1 = cnt[N_ + i], c2 = cnt[2 * N_ + i];
        cursor[i]          = off;
        cursor[N_ + i]     = off + c0;
        cursor[2 * N_ + i] = off + c0 + c1;
        cursor[3 * N_ + i] = off + c0 + c1 + c2;
    }
    if (i == 0) offs[n] = total;
}

// per edge: record {rowidx = r*N+src, w = 1/deg_r(dst)} at CSR position
// after this kernel, cursor[r*N+d] == segment END for (rel r, node d)
__global__ void k_fill(const int* __restrict__ src, const int* __restrict__ dst,
                       const int* __restrict__ cnt, int* __restrict__ cursor,
                       uint2* __restrict__ ue, int E, int RE, int N) {
    int i = blockIdx.x * blockDim.x + threadIdx.x;
    if (i >= RE) return;
    int r = i / E;
    int d = dst[i];
    int pos = atomicAdd(&cursor[r * N + d], 1);
    float w = 1.0f / (float)max(cnt[r * N + d], 1);
    ue[pos] = make_uint2((unsigned)(r * N + src[i]), __float_as_uint(w));
}

// ---------- Layer 1: 16 lanes per node (4 nodes/wave), uint4 gathers, unroll 2 ----------
__global__ void k_pull1(const unsigned short* __restrict__ eb, const int* __restrict__ offs2,
                        const uint2* __restrict__ ue, const float* __restrict__ bias1,
                        unsigned short* __restrict__ h1, int N) {
    int node = blockIdx.x * 16 + (threadIdx.x >> 4);
    if (node >= N) return;
    int q = threadIdx.x & 15;
    int beg = offs2[node], end = offs2[node + 1];
    unsigned N1 = (unsigned)N, N2 = (unsigned)(2 * N);

    float a[8] = {0.f, 0.f, 0.f, 0.f, 0.f, 0.f, 0.f, 0.f};
    float c[8] = {0.f, 0.f, 0.f, 0.f, 0.f, 0.f, 0.f, 0.f};

    int e = beg;
    for (; e + 2 <= end; e += 2) {
        uint2 p0 = ue[e], p1 = ue[e + 1];
        unsigned s0 = p0.x; if (s0 >= N2) s0 -= N2; if (s0 >= N1) s0 -= N1;
        unsigned s1 = p1.x; if (s1 >= N2) s1 -= N2; if (s1 >= N1) s1 -= N1;
        float w0 = __uint_as_float(p0.y), w1 = __uint_as_float(p1.y);
        uint4 u0 = *(const uint4*)(eb + (size_t)s0 * H + q * 8);
        uint4 u1 = *(const uint4*)(eb + (size_t)s1 * H + q * 8);
        ACC8(a, u0, w0);
        ACC8(c, u1, w1);
    }
    if (e < end) {
        uint2 p0 = ue[e];
        unsigned s0 = p0.x; if (s0 >= N2) s0 -= N2; if (s0 >= N1) s0 -= N1;
        float w0 = __uint_as_float(p0.y);
        uint4 u0 = *(const uint4*)(eb + (size_t)s0 * H + q * 8);
        ACC8(a, u0, w0);
    }

    float4 b0 = *(const float4*)(bias1 + q * 8);
    float4 b1 = *(const float4*)(bias1 + q * 8 + 4);
    float f0 = fmaxf(a[0] + c[0] + b0.x, 0.f);
    float f1 = fmaxf(a[1] + c[1] + b0.y, 0.f);
    float f2 = fmaxf(a[2] + c[2] + b0.z, 0.f);
    float f3 = fmaxf(a[3] + c[3] + b0.w, 0.f);
    float f4 = fmaxf(a[4] + c[4] + b1.x, 0.f);
    float f5 = fmaxf(a[5] + c[5] + b1.y, 0.f);
    float f6 = fmaxf(a[6] + c[6] + b1.z, 0.f);
    float f7 = fmaxf(a[7] + c[7] + b1.w, 0.f);
    uint4 o;
    o.x = (unsigned)f2b(f0) | ((unsigned)f2b(f1) << 16);
    o.y = (unsigned)f2b(f2) | ((unsigned)f2b(f3) << 16);
    o.z = (unsigned)f2b(f4) | ((unsigned)f2b(f5) << 16);
    o.w = (unsigned)f2b(f6) | ((unsigned)f2b(f7) << 16);
    *(uint4*)(h1 + (size_t)node * H + q * 8) = o;
}

// ---------- Layer 2 FUSED: out = bias2 + sum_r mean_r(h1[src]) @ W_r ----------
// Wave handles 16 nodes (one MFMA M-tile). Lane l pulls node node0+(l&15),
// features {(l>>4)*8 + kk*32} — exactly its 16x16x32 A-fragment slices.
// Per relation: register aggregate -> bf16 frags -> MFMA vs WT2 (B^T [64][512]).
// C accumulates f32 over relations; stored directly to out + bias2. No LDS, no T.
__global__ __launch_bounds__(256) void k_l2(const unsigned short* __restrict__ h1,
                                            const int* __restrict__ cursor,
                                            const int* __restrict__ cnt,
                                            const uint2* __restrict__ ue,
                                            const unsigned short* __restrict__ WT2,
                                            const float* __restrict__ bias2,
                                            float* __restrict__ out, int N) {
    int l = threadIdx.x & 63;
    int wv = threadIdx.x >> 6;
    int node0 = blockIdx.x * 64 + wv * 16;
    int rA = l & 15, q = l >> 4;
    int node = node0 + rA;

    f32x4 z = {0.f, 0.f, 0.f, 0.f};
    f32x4 cacc[4] = {z, z, z, z};

    for (int r = 0; r < RELS; ++r) {
        int rN = r * N;
        int end_ = 0, c_ = 0;
        if (node < N) { end_ = cursor[rN + node]; c_ = cnt[rN + node]; }
        int beg = end_ - c_;

        float acc[32];
#pragma unroll
        for (int i = 0; i < 32; ++i) acc[i] = 0.f;

        int e = beg;
        for (; e + 2 <= end_; e += 2) {
            uint2 p0 = ue[e], p1 = ue[e + 1];
            unsigned s0 = p0.x - (unsigned)rN;
            unsigned s1 = p1.x - (unsigned)rN;
            float w0 = __uint_as_float(p0.y), w1 = __uint_as_float(p1.y);
            const unsigned short* r0 = h1 + (size_t)s0 * H + q * 8;
            const unsigned short* r1 = h1 + (size_t)s1 * H + q * 8;
            uint4 u0 = *(const uint4*)(r0);
            uint4 u1 = *(const uint4*)(r0 + 32);
            uint4 u2 = *(const uint4*)(r0 + 64);
            uint4 u3 = *(const uint4*)(r0 + 96);
            uint4 v0 = *(const uint4*)(r1);
            uint4 v1 = *(const uint4*)(r1 + 32);
            uint4 v2 = *(const uint4*)(r1 + 64);
            uint4 v3 = *(const uint4*)(r1 + 96);
            ACC8B(acc, 0,  u0, w0); ACC8B(acc, 8,  u1, w0);
            ACC8B(acc, 16, u2, w0); ACC8B(acc, 24, u3, w0);
            ACC8B(acc, 0,  v0, w1); ACC8B(acc, 8,  v1, w1);
            ACC8B(acc, 16, v2, w1); ACC8B(acc, 24, v3, w1);
        }
        if (e < end_) {
            uint2 p0 = ue[e];
            unsigned s0 = p0.x - (unsigned)rN;
            float w0 = __uint_as_float(p0.y);
            const unsigned short* r0 = h1 + (size_t)s0 * H + q * 8;
            uint4 u0 = *(const uint4*)(r0);
            uint4 u1 = *(const uint4*)(r0 + 32);
            uint4 u2 = *(const uint4*)(r0 + 64);
            uint4 u3 = *(const uint4*)(r0 + 96);
            ACC8B(acc, 0,  u0, w0); ACC8B(acc, 8,  u1, w0);
            ACC8B(acc, 16, u2, w0); ACC8B(acc, 24, u3, w0);
        }

        // convert to the 4 A-fragments (af[kk][j] = bf16(acc[kk*8+j]))
        short8 af[4];
#pragma unroll
        for (int kk = 0; kk < 4; ++kk)
#pragma unroll
            for (int j = 0; j < 8; ++j)
                af[kk][j] = (short)f2b(acc[kk * 8 + j]);

#pragma unroll
        for (int kk = 0; kk < 4; ++kk)
#pragma unroll
            for (int nt = 0; nt < 4; ++nt) {
                short8 bf = *(const short8*)(WT2 + ((size_t)(nt * 16 + rA)) * 512
                                             + r * H + kk * 32 + q * 8);
                cacc[nt] = __builtin_amdgcn_mfma_f32_16x16x32_bf16(af[kk], bf, cacc[nt], 0, 0, 0);
            }
    }

    // C layout: col = l&15 (rA), row = q*4 + j
#pragma unroll
    for (int nt = 0; nt < 4; ++nt) {
        int col = nt * 16 + rA;
        float b2 = bias2[col];
#pragma unroll
        for (int j = 0; j < 4; ++j) {
            int nrow = node0 + q * 4 + j;
            if (nrow < N) out[(size_t)nrow * O + col] = cacc[nt][j] + b2;
        }
    }
}

extern "C" void kernel_launch(void* const* d_in, const int* in_sizes, int n_in,
                              void* d_out, int out_size, void* d_ws, size_t ws_size,
                              hipStream_t stream) {
    const float* embed  = (const float*)d_in[0];
    const float* weight = (const float*)d_in[1];
    const float* bias1  = (const float*)d_in[2];
    const float* bias2  = (const float*)d_in[3];
    const int*   esrc   = (const int*)d_in[4];
    const int*   edst   = (const int*)d_in[5];
    float* out = (float*)d_out;

    const int N = in_sizes[0] / H;
    const int E = in_sizes[4] / RELS;
    const int RN = RELS * N;
    const int RE = RELS * E;

    char* p = (char*)d_ws;
    auto alloc = [&](size_t bytes) {
        char* q = p;
        p += (bytes + 255) & ~(size_t)255;
        return q;
    };
    int* cnt    = (int*)alloc((size_t)RN * 4);
    int* offs2  = (int*)alloc(((size_t)N + 1) * 4);
    int* cursor = (int*)alloc((size_t)RN * 4);
    int* bsum   = (int*)alloc(4096);
    uint2* ue   = (uint2*)alloc((size_t)RE * 8);
    unsigned short* eb  = (unsigned short*)alloc((size_t)N * H * 2);
    unsigned short* h1  = (unsigned short*)alloc((size_t)N * H * 2);
    unsigned short* WT2 = (unsigned short*)alloc((size_t)O * RELS * H * 2);  // [64][512]

    hipMemsetAsync(cnt, 0, (size_t)RN * 4, stream);

    int n4 = N * H / 4;
    int wtot = O * RELS * H;           // 32768
    int b_cvt = (n4 + 1023) / 1024;
    int b_w   = (wtot + 255) / 256;
    int b_h   = (RE + 255) / 256;
    k_prep<<<b_cvt + b_w + b_h, 256, 0, stream>>>(embed, eb, weight, WT2, edst, cnt,
                                                  n4, wtot, E, RE, N, b_cvt, b_w);

    int nb = (N + 1023) / 1024;
    k_scan1<<<nb, 256, 0, stream>>>(cnt, offs2, bsum, N, N);
    k_scan2<<<1, 512, 0, stream>>>(bsum, nb);
    k_scan3c<<<(N + 255) / 256, 256, 0, stream>>>(offs2, bsum, cnt, cursor, N, RE, N);

    k_fill<<<(RE + 255) / 256, 256, 0, stream>>>(esrc, edst, cnt, cursor, ue, E, RE, N);

    k_pull1<<<(N + 15) / 16, 256, 0, stream>>>(eb, offs2, ue, bias1, h1, N);

    k_l2<<<(N + 63) / 64, 256, 0, stream>>>(h1, cursor, cnt, ue, WT2, bias2, out, N);
}

// Round 8
// 176.084 us; speedup vs baseline: 1.1852x; 1.1852x over previous
//
#include <hip/hip_runtime.h>
#include <hip/hip_bf16.h>

#define H 128
#define O 64
#define RELS 4

typedef short short8 __attribute__((ext_vector_type(8)));
typedef float f32x4 __attribute__((ext_vector_type(4)));

static __device__ __forceinline__ unsigned short f2b(float x) {
    __hip_bfloat16 h = __float2bfloat16(x);           // RNE
    return *reinterpret_cast<unsigned short*>(&h);
}
static __device__ __forceinline__ float blo(unsigned u) { return __uint_as_float(u << 16); }
static __device__ __forceinline__ float bhi(unsigned u) { return __uint_as_float(u & 0xffff0000u); }

// NOTE: parameter names must not collide with vector member names (.x/.y/.z/.w)
#define ACC8(acc, uv, wt)                                           \
    acc[0] += (wt) * blo(uv.x); acc[1] += (wt) * bhi(uv.x);         \
    acc[2] += (wt) * blo(uv.y); acc[3] += (wt) * bhi(uv.y);         \
    acc[4] += (wt) * blo(uv.z); acc[5] += (wt) * bhi(uv.z);         \
    acc[6] += (wt) * blo(uv.w); acc[7] += (wt) * bhi(uv.w);

// ---------- fused prep: embed->bf16 (4x ILP), W->WT [r][n][k] bf16, dst histogram ----------
__global__ void k_prep(const float* __restrict__ embed, unsigned short* __restrict__ eb,
                       const float* __restrict__ W, unsigned short* __restrict__ WT,
                       const int* __restrict__ dst, int* __restrict__ cnt,
                       int n4, int wtot, int E, int RE, int N, int b_cvt, int b_w) {
    int b = blockIdx.x;
    if (b < b_cvt) {
        int base = b * 1024;
#pragma unroll
        for (int k = 0; k < 4; ++k) {
            int i = base + k * 256 + threadIdx.x;
            if (i < n4) {
                float4 v = ((const float4*)embed)[i];
                ushort4 o;
                o.x = f2b(v.x); o.y = f2b(v.y); o.z = f2b(v.z); o.w = f2b(v.w);
                ((ushort4*)eb)[i] = o;
            }
        }
    } else if (b < b_cvt + b_w) {
        int i = (b - b_cvt) * 256 + threadIdx.x;
        if (i < wtot) {
            int r = i >> 13;            // O*H = 8192
            int n = (i >> 7) & (O - 1);
            int k = i & (H - 1);
            WT[i] = f2b(W[((size_t)r * H + k) * O + n]);
        }
    } else {
        int i = (b - b_cvt - b_w) * 256 + threadIdx.x;
        if (i < RE) { int r = i / E; atomicAdd(&cnt[r * N + dst[i]], 1); }
    }
}

// ---------- scan1 with fused per-node total (totdeg = sum_r cnt[r*N+i]) ----------
__global__ void k_scan1(const int* __restrict__ cnt, int* __restrict__ offs,
                        int* __restrict__ bsum, int n, int N_) {
    __shared__ int sh[256];
    int t = threadIdx.x;
    int base = blockIdx.x * 1024 + t * 4;
    int4 v = make_int4(0, 0, 0, 0);
    if (base + 3 < n && (N_ & 3) == 0) {
#pragma unroll
        for (int r = 0; r < RELS; ++r) {
            int4 c = *(const int4*)(cnt + (size_t)r * N_ + base);
            v.x += c.x; v.y += c.y; v.z += c.z; v.w += c.w;
        }
    } else {
        for (int j = 0; j < 4; ++j) {
            int i = base + j;
            if (i < n) {
                int s = 0;
                for (int r = 0; r < RELS; ++r) s += cnt[(size_t)r * N_ + i];
                (&v.x)[j] = s;
            }
        }
    }
    int s = v.x + v.y + v.z + v.w;
    sh[t] = s; __syncthreads();
    for (int off = 1; off < 256; off <<= 1) {
        int x = (t >= off) ? sh[t - off] : 0;
        __syncthreads();
        sh[t] += x;
        __syncthreads();
    }
    int incl = sh[t];
    int ex = incl - s;
    if (base < n)     offs[base]     = ex;
    if (base + 1 < n) offs[base + 1] = ex + v.x;
    if (base + 2 < n) offs[base + 2] = ex + v.x + v.y;
    if (base + 3 < n) offs[base + 3] = ex + v.x + v.y + v.z;
    if (t == 255) bsum[blockIdx.x] = incl;
}

__global__ void k_scan2(int* __restrict__ bsum, int nb) {
    __shared__ int sh[512];
    int t = threadIdx.x;
    int s = (t < nb) ? bsum[t] : 0;
    sh[t] = s; __syncthreads();
    for (int off = 1; off < 512; off <<= 1) {
        int x = (t >= off) ? sh[t - off] : 0;
        __syncthreads();
        sh[t] += x;
        __syncthreads();
    }
    if (t < nb) bsum[t] = sh[t] - s;
}

// finalize offs + build per-(rel,node) cursors
__global__ void k_scan3c(int* __restrict__ offs, const int* __restrict__ bsum,
                         const int* __restrict__ cnt, int* __restrict__ cursor,
                         int n, int total, int N_) {
    int i = blockIdx.x * blockDim.x + threadIdx.x;
    if (i < n) {
        int off = offs[i] + bsum[i >> 10];
        offs[i] = off;
        int c0 = cnt[i], c1 = cnt[N_ + i], c2 = cnt[2 * N_ + i];
        cursor[i]          = off;
        cursor[N_ + i]     = off + c0;
        cursor[2 * N_ + i] = off + c0 + c1;
        cursor[3 * N_ + i] = off + c0 + c1 + c2;
    }
    if (i == 0) offs[n] = total;
}

// per edge: record {rowidx = r*N+src, w = 1/deg_r(dst)} at CSR position
__global__ void k_fill(const int* __restrict__ src, const int* __restrict__ dst,
                       const int* __restrict__ cnt, int* __restrict__ cursor,
                       uint2* __restrict__ ue, int E, int RE, int N) {
    int i = blockIdx.x * blockDim.x + threadIdx.x;
    if (i >= RE) return;
    int r = i / E;
    int d = dst[i];
    int pos = atomicAdd(&cursor[r * N + d], 1);
    float w = 1.0f / (float)max(cnt[r * N + d], 1);
    ue[pos] = make_uint2((unsigned)(r * N + src[i]), __float_as_uint(w));
}

// ---------- Layer 1: 16 lanes per node (4 nodes/wave), uint4 gathers, unroll 2 ----------
__global__ void k_pull1(const unsigned short* __restrict__ eb, const int* __restrict__ offs2,
                        const uint2* __restrict__ ue, const float* __restrict__ bias1,
                        unsigned short* __restrict__ h1, int N) {
    int node = blockIdx.x * 16 + (threadIdx.x >> 4);
    if (node >= N) return;
    int q = threadIdx.x & 15;
    int beg = offs2[node], end = offs2[node + 1];
    unsigned N1 = (unsigned)N, N2 = (unsigned)(2 * N);

    float a[8] = {0.f, 0.f, 0.f, 0.f, 0.f, 0.f, 0.f, 0.f};
    float c[8] = {0.f, 0.f, 0.f, 0.f, 0.f, 0.f, 0.f, 0.f};

    int e = beg;
    for (; e + 2 <= end; e += 2) {
        uint2 p0 = ue[e], p1 = ue[e + 1];
        unsigned s0 = p0.x; if (s0 >= N2) s0 -= N2; if (s0 >= N1) s0 -= N1;
        unsigned s1 = p1.x; if (s1 >= N2) s1 -= N2; if (s1 >= N1) s1 -= N1;
        float w0 = __uint_as_float(p0.y), w1 = __uint_as_float(p1.y);
        uint4 u0 = *(const uint4*)(eb + (size_t)s0 * H + q * 8);
        uint4 u1 = *(const uint4*)(eb + (size_t)s1 * H + q * 8);
        ACC8(a, u0, w0);
        ACC8(c, u1, w1);
    }
    if (e < end) {
        uint2 p0 = ue[e];
        unsigned s0 = p0.x; if (s0 >= N2) s0 -= N2; if (s0 >= N1) s0 -= N1;
        float w0 = __uint_as_float(p0.y);
        uint4 u0 = *(const uint4*)(eb + (size_t)s0 * H + q * 8);
        ACC8(a, u0, w0);
    }

    float4 b0 = *(const float4*)(bias1 + q * 8);
    float4 b1 = *(const float4*)(bias1 + q * 8 + 4);
    float f0 = fmaxf(a[0] + c[0] + b0.x, 0.f);
    float f1 = fmaxf(a[1] + c[1] + b0.y, 0.f);
    float f2 = fmaxf(a[2] + c[2] + b0.z, 0.f);
    float f3 = fmaxf(a[3] + c[3] + b0.w, 0.f);
    float f4 = fmaxf(a[4] + c[4] + b1.x, 0.f);
    float f5 = fmaxf(a[5] + c[5] + b1.y, 0.f);
    float f6 = fmaxf(a[6] + c[6] + b1.z, 0.f);
    float f7 = fmaxf(a[7] + c[7] + b1.w, 0.f);
    uint4 o;
    o.x = (unsigned)f2b(f0) | ((unsigned)f2b(f1) << 16);
    o.y = (unsigned)f2b(f2) | ((unsigned)f2b(f3) << 16);
    o.z = (unsigned)f2b(f4) | ((unsigned)f2b(f5) << 16);
    o.w = (unsigned)f2b(f6) | ((unsigned)f2b(f7) << 16);
    *(uint4*)(h1 + (size_t)node * H + q * 8) = o;
}

// ---------- Layer 2 GEMM (MFMA bf16), relation-parallel waves ----------
// Block = one 32-row tile; wave wv computes T[wv] = rows @ W[wv].
// 4x the waves of the row-only split -> occupancy, not BW, was the limit.
__global__ __launch_bounds__(256) void k_gemm(const unsigned short* __restrict__ h1,
                                              const unsigned short* __restrict__ WT,
                                              unsigned short* __restrict__ T, int N) {
    __shared__ __align__(16) unsigned short st[4][32][72];
    int tid = threadIdx.x, wv = tid >> 6, l = tid & 63;
    int row0 = blockIdx.x * 32;
    int rA = l & 15, kb = (l >> 4) * 8;

    short8 af[2][4];
#pragma unroll
    for (int mf = 0; mf < 2; ++mf)
#pragma unroll
        for (int kk = 0; kk < 4; ++kk) {
            int row = row0 + mf * 16 + rA;
            short8 v = {0, 0, 0, 0, 0, 0, 0, 0};
            if (row < N) v = *(const short8*)(h1 + (size_t)row * H + kk * 32 + kb);
            af[mf][kk] = v;
        }

    const unsigned short* Wb = WT + (size_t)wv * O * H;
    f32x4 z = {0.f, 0.f, 0.f, 0.f};
    f32x4 acc[2][4];
#pragma unroll
    for (int mf = 0; mf < 2; ++mf)
#pragma unroll
        for (int nt = 0; nt < 4; ++nt) acc[mf][nt] = z;

#pragma unroll
    for (int nt = 0; nt < 4; ++nt) {
        short8 bf[4];
#pragma unroll
        for (int kk = 0; kk < 4; ++kk)
            bf[kk] = *(const short8*)(Wb + ((size_t)(nt * 16 + rA)) * H + kk * 32 + kb);
#pragma unroll
        for (int kk = 0; kk < 4; ++kk)
#pragma unroll
            for (int mf = 0; mf < 2; ++mf)
                acc[mf][nt] = __builtin_amdgcn_mfma_f32_16x16x32_bf16(
                    af[mf][kk], bf[kk], acc[mf][nt], 0, 0, 0);
    }

    // C layout: col = l&15, row = (l>>4)*4 + j  -> wave-private LDS transpose
#pragma unroll
    for (int mf = 0; mf < 2; ++mf)
#pragma unroll
        for (int nt = 0; nt < 4; ++nt)
#pragma unroll
            for (int j = 0; j < 4; ++j)
                st[wv][mf * 16 + (l >> 4) * 4 + j][nt * 16 + rA] = f2b(acc[mf][nt][j]);

#pragma unroll
    for (int i = 0; i < 4; ++i) {
        int rr = i * 8 + (l >> 3);
        uint4 v = *(const uint4*)&st[wv][rr][(l & 7) * 8];
        int grow = row0 + rr;
        if (grow < N)
            *(uint4*)(T + ((size_t)wv * N + grow) * O + (l & 7) * 8) = v;
    }
}

// ---------- Layer 2: 8 lanes per node (8 nodes/wave), uint4 gathers, unroll 2 ----------
__global__ void k_pull2(const unsigned short* __restrict__ T, const int* __restrict__ offs2,
                        const uint2* __restrict__ ue, const float* __restrict__ bias2,
                        float* __restrict__ out, int N) {
    int node = blockIdx.x * 32 + (threadIdx.x >> 3);
    if (node >= N) return;
    int o = threadIdx.x & 7;
    int beg = offs2[node], end = offs2[node + 1];

    float a[8] = {0.f, 0.f, 0.f, 0.f, 0.f, 0.f, 0.f, 0.f};
    float c[8] = {0.f, 0.f, 0.f, 0.f, 0.f, 0.f, 0.f, 0.f};

    int e = beg;
    for (; e + 2 <= end; e += 2) {
        uint2 p0 = ue[e], p1 = ue[e + 1];
        float w0 = __uint_as_float(p0.y), w1 = __uint_as_float(p1.y);
        uint4 u0 = *(const uint4*)(T + (size_t)p0.x * O + o * 8);
        uint4 u1 = *(const uint4*)(T + (size_t)p1.x * O + o * 8);
        ACC8(a, u0, w0);
        ACC8(c, u1, w1);
    }
    if (e < end) {
        uint2 p0 = ue[e];
        float w0 = __uint_as_float(p0.y);
        uint4 u0 = *(const uint4*)(T + (size_t)p0.x * O + o * 8);
        ACC8(a, u0, w0);
    }

    float4 b0 = *(const float4*)(bias2 + o * 8);
    float4 b1 = *(const float4*)(bias2 + o * 8 + 4);
    float4 v0, v1;
    v0.x = a[0] + c[0] + b0.x; v0.y = a[1] + c[1] + b0.y;
    v0.z = a[2] + c[2] + b0.z; v0.w = a[3] + c[3] + b0.w;
    v1.x = a[4] + c[4] + b1.x; v1.y = a[5] + c[5] + b1.y;
    v1.z = a[6] + c[6] + b1.z; v1.w = a[7] + c[7] + b1.w;
    *(float4*)(out + (size_t)node * O + o * 8)     = v0;
    *(float4*)(out + (size_t)node * O + o * 8 + 4) = v1;
}

extern "C" void kernel_launch(void* const* d_in, const int* in_sizes, int n_in,
                              void* d_out, int out_size, void* d_ws, size_t ws_size,
                              hipStream_t stream) {
    const float* embed  = (const float*)d_in[0];
    const float* weight = (const float*)d_in[1];
    const float* bias1  = (const float*)d_in[2];
    const float* bias2  = (const float*)d_in[3];
    const int*   esrc   = (const int*)d_in[4];
    const int*   edst   = (const int*)d_in[5];
    float* out = (float*)d_out;

    const int N = in_sizes[0] / H;
    const int E = in_sizes[4] / RELS;
    const int RN = RELS * N;
    const int RE = RELS * E;

    char* p = (char*)d_ws;
    auto alloc = [&](size_t bytes) {
        char* q = p;
        p += (bytes + 255) & ~(size_t)255;
        return q;
    };
    int* cnt    = (int*)alloc((size_t)RN * 4);
    int* offs2  = (int*)alloc(((size_t)N + 1) * 4);
    int* cursor = (int*)alloc((size_t)RN * 4);
    int* bsum   = (int*)alloc(4096);
    uint2* ue   = (uint2*)alloc((size_t)RE * 8);
    unsigned short* eb  = (unsigned short*)alloc((size_t)N * H * 2);
    unsigned short* h1  = (unsigned short*)alloc((size_t)N * H * 2);
    unsigned short* WT  = (unsigned short*)alloc((size_t)RELS * O * H * 2);
    unsigned short* T   = (unsigned short*)alloc((size_t)RELS * N * O * 2);

    hipMemsetAsync(cnt, 0, (size_t)RN * 4, stream);

    int n4 = N * H / 4;
    int wtot = RELS * O * H;
    int b_cvt = (n4 + 1023) / 1024;
    int b_w   = (wtot + 255) / 256;
    int b_h   = (RE + 255) / 256;
    k_prep<<<b_cvt + b_w + b_h, 256, 0, stream>>>(embed, eb, weight, WT, edst, cnt,
                                                  n4, wtot, E, RE, N, b_cvt, b_w);

    int nb = (N + 1023) / 1024;
    k_scan1<<<nb, 256, 0, stream>>>(cnt, offs2, bsum, N, N);
    k_scan2<<<1, 512, 0, stream>>>(bsum, nb);
    k_scan3c<<<(N + 255) / 256, 256, 0, stream>>>(offs2, bsum, cnt, cursor, N, RE, N);

    k_fill<<<(RE + 255) / 256, 256, 0, stream>>>(esrc, edst, cnt, cursor, ue, E, RE, N);

    k_pull1<<<(N + 15) / 16, 256, 0, stream>>>(eb, offs2, ue, bias1, h1, N);

    k_gemm<<<(N + 31) / 32, 256, 0, stream>>>(h1, WT, T, N);

    k_pull2<<<(N + 31) / 32, 256, 0, stream>>>(T, offs2, ue, bias2, out, N);
}